// Round 9
// baseline (338.204 us; speedup 1.0000x reference)
//
#include <hip/hip_runtime.h>

#define HID 10
#define STEPS 512

typedef __attribute__((ext_vector_type(2))) float v2f;
typedef __attribute__((ext_vector_type(4))) float v4f;

// broadcast lane ((lane&0x10)|F) within each 32-lane half -> all lanes of each 16-group
// (one-time use: t=0 peel)
template<int F>
static __device__ __forceinline__ float swz(float v) {
    return __int_as_float(__builtin_amdgcn_ds_swizzle(__float_as_int(v), (F << 5) | 0x10));
}

// Lane-parallel fused GRU decoder, 1 feature per lane, EIGHT batches per wave
// as two independent in-wave streams (A = blockIdx*8+g, B = +4), grid 1024.
// v9 = v8 + de-serialization of the two streams:
//   v8 post-mortem: issue 449 cyc (same as v7's 434 -> tables shared OK) but
//   stall 470 = 2x(DS roundtrip) + 2x(trans tail): the streams ran SERIALLY.
//   VGPR_Count=64 is the tell — the compiler's occupancy-targeting heuristic
//   compressed pressure by serializing stream dataflows (interleaved needs ~110).
// Fixes: (1) amdgpu_waves_per_eu(1,1) pins the occupancy target -> 256-VGPR
//   budget (R3 proved the attribute changes allocation); (2) trans chains and
//   dot families hand-interleaved in source; (3) DS batched: writeA,writeB,
//   then all 6 reads -> the two roundtrips overlap in the in-order DS pipe,
//   and qA's lgkmcnt(3) wait does not cover qB's reads.
__attribute__((amdgpu_waves_per_eu(1, 1)))
__global__ __launch_bounds__(64) void gru_decoder_kernel(
    const float* __restrict__ hidden, const float* __restrict__ w_ih,
    const float* __restrict__ w_hh, const float* __restrict__ b_ih,
    const float* __restrict__ b_hh, const float* __restrict__ l1_w,
    const float* __restrict__ l1_b, const float* __restrict__ l2_w,
    const float* __restrict__ l2_b, float* __restrict__ out)
{
    __shared__ float sWx[640];   // l2_w @ l1_w (64x10)
    __shared__ float sbx[64];    // l2_w @ l1_b + l2_b
    __shared__ float sWgi[300];  // w_ih @ Wx (30x10)
    __shared__ float sbgi[30];   // b_ih + w_ih @ bx
    __shared__ float sWhh[300];  // w_hh copy (t=0 peel + weight build)
    __shared__ float sH[128];    // 8 rows x 16 floats (A: rows 0-3, B: rows 4-7)

    const int lane = threadIdx.x;
    const int f    = lane & 15;
    const int g    = lane >> 4;
    const int bA   = blockIdx.x * 8 + g;
    const int bB   = bA + 4;
    const bool ok  = (f < HID);
    const int fi   = ok ? f : 0;          // clamped index for safe reads

    // ---- preamble: fused weights (fp32, cooperative) ----
    for (int e = lane; e < 640; e += 64) {
        int i = e / 10, j = e - i * 10;
        float acc = 0.f;
        #pragma unroll
        for (int k = 0; k < 10; ++k) acc += l2_w[i * 10 + k] * l1_w[k * 10 + j];
        sWx[e] = acc;
    }
    {
        float acc = l2_b[lane];
        #pragma unroll
        for (int k = 0; k < 10; ++k) acc += l2_w[lane * 10 + k] * l1_b[k];
        sbx[lane] = acc;
    }
    for (int e = lane; e < 300; e += 64) sWhh[e] = w_hh[e];
    __syncthreads();
    for (int e = lane; e < 300; e += 64) {
        int m = e / 10, j = e - m * 10;
        float acc = 0.f;
        for (int k = 0; k < 64; ++k) acc += w_ih[m * 64 + k] * sWx[k * 10 + j];
        sWgi[e] = acc;
    }
    if (lane < 30) {
        float acc = b_ih[lane];
        for (int k = 0; k < 64; ++k) acc += w_ih[lane * 64 + k] * sbx[k];
        sbgi[lane] = acc;
    }
    __syncthreads();

    const float LOG2E = 1.4426950408889634f;
    const float S2    = 2.f * LOG2E;

    // ---- per-lane weights (feature fi), packed across k (even/odd); shared A/B ----
    v2f wr2[5], wz2[5], wi2[5], wh2[5], wo2[5];
    #pragma unroll
    for (int k2 = 0; k2 < 5; ++k2) {
        int k0 = 2 * k2, k1 = 2 * k2 + 1;
        float r0 = -(sWgi[fi * 10 + k0] + sWhh[fi * 10 + k0]) * LOG2E;
        float r1 = -(sWgi[fi * 10 + k1] + sWhh[fi * 10 + k1]) * LOG2E;
        float z0 = -(sWgi[(10 + fi) * 10 + k0] + sWhh[(10 + fi) * 10 + k0]) * LOG2E;
        float z1 = -(sWgi[(10 + fi) * 10 + k1] + sWhh[(10 + fi) * 10 + k1]) * LOG2E;
        float i0 = sWgi[(20 + fi) * 10 + k0] * S2;
        float i1 = sWgi[(20 + fi) * 10 + k1] * S2;
        float hh0 = sWhh[(20 + fi) * 10 + k0] * S2;
        float hh1 = sWhh[(20 + fi) * 10 + k1] * S2;
        float o0 = l1_w[fi * 10 + k0];
        float o1 = l1_w[fi * 10 + k1];
        wr2[k2] = ok ? v2f{r0, r1}   : v2f{0.f, 0.f};
        wz2[k2] = ok ? v2f{z0, z1}   : v2f{0.f, 0.f};
        wi2[k2] = ok ? v2f{i0, i1}   : v2f{0.f, 0.f};
        wh2[k2] = ok ? v2f{hh0, hh1} : v2f{0.f, 0.f};
        wo2[k2] = ok ? v2f{o0, o1}   : v2f{0.f, 0.f};
    }
    const float br = ok ? -(sbgi[fi] + b_hh[fi]) * LOG2E : 0.f;
    const float bz = ok ? -(sbgi[10 + fi] + b_hh[10 + fi]) * LOG2E : 0.f;
    const float bi = ok ? sbgi[20 + fi] * S2 : 0.f;
    const float bh = ok ? b_hh[20 + fi] * S2 : 0.f;
    const float bo = ok ? l1_b[fi] : 0.f;
    const v2f BR2 = {br, 0.f}, BZ2 = {bz, 0.f}, BI2 = {bi, 0.f},
              BH2 = {bh, 0.f}, BO2 = {bo, 0.f};
    // t=0 peel biases (gi = b_ih only)
    const float br0_ = ok ? -(b_ih[fi] + b_hh[fi]) * LOG2E : 0.f;
    const float bz0_ = ok ? -(b_ih[10 + fi] + b_hh[10 + fi]) * LOG2E : 0.f;
    const float bni0 = ok ? b_ih[20 + fi] * S2 : 0.f;

    // ---- initial h for both streams (f>=10 stays exactly 0) ----
    float hA = ok ? hidden[(size_t)bA * HID + f] : 0.f;
    float hB = ok ? hidden[(size_t)bB * HID + f] : 0.f;

    float* pbA = out + (size_t)bA * (STEPS * HID) + (size_t)(STEPS - 1) * HID + f;
    float* pbB = out + (size_t)bB * (STEPS * HID) + (size_t)(STEPS - 1) * HID + f;
    float* rowA = &sH[g * 16];
    float* rowB = &sH[(4 + g) * 16];

    // ---- t = 0 peel (gi = b_ih only; x_0 = 0) for both streams ----
    auto peel0 = [&](float& h) {
        float ha[10];
        ha[0] = swz<0>(h); ha[1] = swz<1>(h); ha[2] = swz<2>(h);
        ha[3] = swz<3>(h); ha[4] = swz<4>(h); ha[5] = swz<5>(h);
        ha[6] = swz<6>(h); ha[7] = swz<7>(h); ha[8] = swz<8>(h);
        ha[9] = swz<9>(h);
        float pr = 0.f, pz = 0.f, ph = 0.f;
        #pragma unroll
        for (int k = 0; k < 10; ++k) {
            pr += sWhh[fi * 10 + k] * ha[k];
            pz += sWhh[(10 + fi) * 10 + k] * ha[k];
            ph += sWhh[(20 + fi) * 10 + k] * ha[k];
        }
        float vr = br0_ - pr * LOG2E;
        float vz = bz0_ - pz * LOG2E;
        float r = __builtin_amdgcn_rcpf(1.f + __builtin_amdgcn_exp2f(vr));
        float z = __builtin_amdgcn_rcpf(1.f + __builtin_amdgcn_exp2f(vz));
        float y = bni0 + r * (ph * S2 + bh);
        float n = 1.f - 2.f * __builtin_amdgcn_rcpf(1.f + __builtin_amdgcn_exp2f(y));
        h = ok ? (n + z * (h - n)) : 0.f;
    };
    peel0(hA);
    peel0(hB);

    // ---- pre-loop stage: write h_1, read gather regs for both streams ----
    rowA[f] = hA;
    rowB[f] = hB;
    __builtin_amdgcn_wave_barrier();      // one-time ordering (outside hot loop)
    v4f qA0 = *(const v4f*)(rowA); v4f qA1 = *(const v4f*)(rowA + 4);
    v2f qA2 = *(const v2f*)(rowA + 8);
    v4f qB0 = *(const v4f*)(rowB); v4f qB1 = *(const v4f*)(rowB + 4);
    v2f qB2 = *(const v2f*)(rowB + 8);

    // ---- t = 1 .. 511 : dual-stream, source-interleaved; batched DS ----
    #pragma unroll 1
    for (int t = 1; t < STEPS; ++t) {
        // unpack gathers
        v2f hA0 = __builtin_shufflevector(qA0, qA0, 0, 1);
        v2f hA1 = __builtin_shufflevector(qA0, qA0, 2, 3);
        v2f hA2 = __builtin_shufflevector(qA1, qA1, 0, 1);
        v2f hA3 = __builtin_shufflevector(qA1, qA1, 2, 3);
        v2f hA4 = qA2;
        v2f hB0 = __builtin_shufflevector(qB0, qB0, 0, 1);
        v2f hB1 = __builtin_shufflevector(qB0, qB0, 2, 3);
        v2f hB2 = __builtin_shufflevector(qB1, qB1, 0, 1);
        v2f hB3 = __builtin_shufflevector(qB1, qB1, 2, 3);
        v2f hB4 = qB2;

        // dots, A/B interleaved (fma-init into bias consts)
        v2f arA = wr2[0] * hA0 + BR2;   v2f arB = wr2[0] * hB0 + BR2;
        v2f azA = wz2[0] * hA0 + BZ2;   v2f azB = wz2[0] * hB0 + BZ2;
        v2f aiA = wi2[0] * hA0 + BI2;   v2f aiB = wi2[0] * hB0 + BI2;
        v2f ahA = wh2[0] * hA0 + BH2;   v2f ahB = wh2[0] * hB0 + BH2;
        v2f aoA = wo2[0] * hA0 + BO2;   v2f aoB = wo2[0] * hB0 + BO2;
        arA += wr2[1] * hA1;  arB += wr2[1] * hB1;
        azA += wz2[1] * hA1;  azB += wz2[1] * hB1;
        aiA += wi2[1] * hA1;  aiB += wi2[1] * hB1;
        ahA += wh2[1] * hA1;  ahB += wh2[1] * hB1;
        aoA += wo2[1] * hA1;  aoB += wo2[1] * hB1;
        arA += wr2[2] * hA2;  arB += wr2[2] * hB2;
        azA += wz2[2] * hA2;  azB += wz2[2] * hB2;
        aiA += wi2[2] * hA2;  aiB += wi2[2] * hB2;
        ahA += wh2[2] * hA2;  ahB += wh2[2] * hB2;
        aoA += wo2[2] * hA2;  aoB += wo2[2] * hB2;
        arA += wr2[3] * hA3;  arB += wr2[3] * hB3;
        azA += wz2[3] * hA3;  azB += wz2[3] * hB3;
        aiA += wi2[3] * hA3;  aiB += wi2[3] * hB3;
        ahA += wh2[3] * hA3;  ahB += wh2[3] * hB3;
        aoA += wo2[3] * hA3;  aoB += wo2[3] * hB3;
        arA += wr2[4] * hA4;  arB += wr2[4] * hB4;
        azA += wz2[4] * hA4;  azB += wz2[4] * hB4;
        aiA += wi2[4] * hA4;  aiB += wi2[4] * hB4;
        ahA += wh2[4] * hA4;  ahB += wh2[4] * hB4;
        aoA += wo2[4] * hA4;  aoB += wo2[4] * hB4;

        float arxA = arA.x + arA.y;   float arxB = arB.x + arB.y;
        float azxA = azA.x + azA.y;   float azxB = azB.x + azB.y;
        float aixA = aiA.x + aiA.y;   float aixB = aiB.x + aiB.y;
        float ahxA = ahA.x + ahA.y;   float ahxB = ahB.x + ahB.y;
        float oA   = aoA.x + aoA.y;   float oB   = aoB.x + aoB.y;  // = o_{t-1}

        // trans tails, interleaved (fused z/n update, single rcp per stream):
        //   h' = (ez*(en-1) + h*(en+1)) / ((en+1)*(1+ez))
        float erA = __builtin_amdgcn_exp2f(arxA);
        float erB = __builtin_amdgcn_exp2f(arxB);
        float rA  = __builtin_amdgcn_rcpf(1.f + erA);
        float rB  = __builtin_amdgcn_rcpf(1.f + erB);
        float ezA = __builtin_amdgcn_exp2f(azxA);
        float ezB = __builtin_amdgcn_exp2f(azxB);
        float yA  = __builtin_fmaf(rA, ahxA, aixA);
        float yB  = __builtin_fmaf(rB, ahxB, aixB);
        float enA = __builtin_amdgcn_exp2f(yA);
        float enB = __builtin_amdgcn_exp2f(yB);
        float pA  = enA * ezA;             float pB  = enB * ezB;
        float uA  = pA + (hA - ezA);       float uB  = pB + (hB - ezB);
        float numA = __builtin_fmaf(hA, enA, uA);
        float numB = __builtin_fmaf(hB, enB, uB);
        float denA = (pA + (enA + ezA)) + 1.f;
        float denB = (pB + (enB + ezB)) + 1.f;
        hA = numA * __builtin_amdgcn_rcpf(denA);   // padded lanes stay 0
        hB = numB * __builtin_amdgcn_rcpf(denB);

        // batched DS: both writes, then all reads (roundtrips overlap in-pipe;
        // aliasing pins each write before its reads)
        rowA[f] = hA;
        rowB[f] = hB;
        qA0 = *(const v4f*)(rowA);
        qA1 = *(const v4f*)(rowA + 4);
        qA2 = *(const v2f*)(rowA + 8);
        qB0 = *(const v4f*)(rowB);
        qB1 = *(const v4f*)(rowB + 4);
        qB2 = *(const v2f*)(rowB + 8);

        // pipelined stores: o_{t-1} at position STEPS-t (fills part of the wait)
        if (ok) { pbA[0] = oA; pbB[0] = oB; }
        pbA -= HID; pbB -= HID;
    }

    // ---- epilogue: o_511 = l1(h_512) at position 0 (qA/qB hold h_512) ----
    {
        v2f aoA = wo2[0] * __builtin_shufflevector(qA0, qA0, 0, 1) + BO2;
        aoA += wo2[1] * __builtin_shufflevector(qA0, qA0, 2, 3);
        aoA += wo2[2] * __builtin_shufflevector(qA1, qA1, 0, 1);
        aoA += wo2[3] * __builtin_shufflevector(qA1, qA1, 2, 3);
        aoA += wo2[4] * qA2;
        v2f aoB = wo2[0] * __builtin_shufflevector(qB0, qB0, 0, 1) + BO2;
        aoB += wo2[1] * __builtin_shufflevector(qB0, qB0, 2, 3);
        aoB += wo2[2] * __builtin_shufflevector(qB1, qB1, 0, 1);
        aoB += wo2[3] * __builtin_shufflevector(qB1, qB1, 2, 3);
        aoB += wo2[4] * qB2;
        if (ok) { pbA[0] = aoA.x + aoA.y; pbB[0] = aoB.x + aoB.y; }
    }
}

extern "C" void kernel_launch(void* const* d_in, const int* in_sizes, int n_in,
                              void* d_out, int out_size, void* d_ws, size_t ws_size,
                              hipStream_t stream) {
    (void)in_sizes; (void)n_in; (void)d_ws; (void)ws_size; (void)out_size;
    dim3 grid(1024), block(64);   // 8 batches/wave (2 streams), 1024 waves = 1/SIMD
    gru_decoder_kernel<<<grid, block, 0, stream>>>(
        (const float*)d_in[0], (const float*)d_in[1], (const float*)d_in[2],
        (const float*)d_in[3], (const float*)d_in[4], (const float*)d_in[5],
        (const float*)d_in[6], (const float*)d_in[7], (const float*)d_in[8],
        (float*)d_out);
}

// Round 10
// 291.325 us; speedup vs baseline: 1.1609x; 1.1609x over previous
//
#include <hip/hip_runtime.h>

#define HID 10
#define STEPS 512

typedef __attribute__((ext_vector_type(2))) float v2f;
typedef __attribute__((ext_vector_type(4))) float v4f;

// broadcast lane ((lane&0x10)|F) within each 32-lane half -> all lanes of each 16-group
// (one-time use: t=0 peel + epilogue)
template<int F>
static __device__ __forceinline__ float swz(float v) {
    return __int_as_float(__builtin_amdgcn_ds_swizzle(__float_as_int(v), (F << 5) | 0x10));
}

// Lane-parallel fused GRU decoder, 1 feature per lane, 4 batches per wave.
//   batch = blockIdx*4 + (lane>>4); f = lane&15 (f>=10: zero-padded, stores masked)
// v10 = v7 (measured best, 154us) with the anti-phase stagger re-keyed.
//   v7 profile: 723 cyc/SIMD-step = 2 x issue(217) + chain(290): co-resident
//   waves stall CONCURRENTLY (lockstep convoy), issue adds serially. An offset
//   of ~chain-stall between the two waves lets each wave's issue fill the
//   other's stall (fluid model: offsets <= L are self-preserving; period
//   2I+L -> ~2I). v7's stagger was keyed on (blockIdx>>3)&3 which is CONSTANT
//   across blockIdx strides that are multiples of 32 — co-resident block pairs
//   (likely b, b+1024 or b, b+256) got IDENTICAL sleeps: no offset was created.
//   Fix: key on the PHYSICAL wave slot, s_getreg(HW_REG_HW_ID).WAVE_ID[3:0] —
//   co-resident waves occupy distinct slots by construction, cannot alias.
//   delay = slot * ~256cy; any distinct pair -> effective offset ~210-300 cyc
//   mod the 723 period. One-time <=1.6us; v8/v9 falsified in-wave ILP (single
//   PC: waitcnt stalls the whole wave), so cross-wave phasing is the lever.
__global__ __launch_bounds__(64, 2) void gru_decoder_kernel(
    const float* __restrict__ hidden, const float* __restrict__ w_ih,
    const float* __restrict__ w_hh, const float* __restrict__ b_ih,
    const float* __restrict__ b_hh, const float* __restrict__ l1_w,
    const float* __restrict__ l1_b, const float* __restrict__ l2_w,
    const float* __restrict__ l2_b, float* __restrict__ out)
{
    __shared__ float sWx[640];   // l2_w @ l1_w (64x10)
    __shared__ float sbx[64];    // l2_w @ l1_b + l2_b
    __shared__ float sWgi[300];  // w_ih @ Wx (30x10)
    __shared__ float sbgi[30];   // b_ih + w_ih @ bx
    __shared__ float sWhh[300];  // w_hh copy (t=0 peel + weight build)
    __shared__ float sH[64];     // 4 groups x 16-float rows (gather staging)

    const int lane = threadIdx.x;
    const int f    = lane & 15;
    const int g    = lane >> 4;
    const int b    = blockIdx.x * 4 + g;
    const bool ok  = (f < HID);
    const int fi   = ok ? f : 0;          // clamped index for safe reads

    // ---- preamble: fused weights (fp32, cooperative) ----
    for (int e = lane; e < 640; e += 64) {
        int i = e / 10, j = e - i * 10;
        float acc = 0.f;
        #pragma unroll
        for (int k = 0; k < 10; ++k) acc += l2_w[i * 10 + k] * l1_w[k * 10 + j];
        sWx[e] = acc;
    }
    {
        float acc = l2_b[lane];
        #pragma unroll
        for (int k = 0; k < 10; ++k) acc += l2_w[lane * 10 + k] * l1_b[k];
        sbx[lane] = acc;
    }
    for (int e = lane; e < 300; e += 64) sWhh[e] = w_hh[e];
    __syncthreads();
    for (int e = lane; e < 300; e += 64) {
        int m = e / 10, j = e - m * 10;
        float acc = 0.f;
        for (int k = 0; k < 64; ++k) acc += w_ih[m * 64 + k] * sWx[k * 10 + j];
        sWgi[e] = acc;
    }
    if (lane < 30) {
        float acc = b_ih[lane];
        for (int k = 0; k < 64; ++k) acc += w_ih[lane * 64 + k] * sbx[k];
        sbgi[lane] = acc;
    }
    __syncthreads();

    const float LOG2E = 1.4426950408889634f;
    const float S2    = 2.f * LOG2E;

    // ---- per-lane weights (feature fi), packed across k (even/odd) ----
    v2f wr2[5], wz2[5], wi2[5], wh2[5], wo2[5];
    #pragma unroll
    for (int k2 = 0; k2 < 5; ++k2) {
        int k0 = 2 * k2, k1 = 2 * k2 + 1;
        float r0 = -(sWgi[fi * 10 + k0] + sWhh[fi * 10 + k0]) * LOG2E;
        float r1 = -(sWgi[fi * 10 + k1] + sWhh[fi * 10 + k1]) * LOG2E;
        float z0 = -(sWgi[(10 + fi) * 10 + k0] + sWhh[(10 + fi) * 10 + k0]) * LOG2E;
        float z1 = -(sWgi[(10 + fi) * 10 + k1] + sWhh[(10 + fi) * 10 + k1]) * LOG2E;
        float i0 = sWgi[(20 + fi) * 10 + k0] * S2;
        float i1 = sWgi[(20 + fi) * 10 + k1] * S2;
        float hh0 = sWhh[(20 + fi) * 10 + k0] * S2;
        float hh1 = sWhh[(20 + fi) * 10 + k1] * S2;
        float o0 = l1_w[fi * 10 + k0];
        float o1 = l1_w[fi * 10 + k1];
        wr2[k2] = ok ? v2f{r0, r1}   : v2f{0.f, 0.f};
        wz2[k2] = ok ? v2f{z0, z1}   : v2f{0.f, 0.f};
        wi2[k2] = ok ? v2f{i0, i1}   : v2f{0.f, 0.f};
        wh2[k2] = ok ? v2f{hh0, hh1} : v2f{0.f, 0.f};
        wo2[k2] = ok ? v2f{o0, o1}   : v2f{0.f, 0.f};
    }
    const float br = ok ? -(sbgi[fi] + b_hh[fi]) * LOG2E : 0.f;
    const float bz = ok ? -(sbgi[10 + fi] + b_hh[10 + fi]) * LOG2E : 0.f;
    const float bi = ok ? sbgi[20 + fi] * S2 : 0.f;
    const float bh = ok ? b_hh[20 + fi] * S2 : 0.f;
    const float bo = ok ? l1_b[fi] : 0.f;
    const v2f BR2 = {br, 0.f}, BZ2 = {bz, 0.f}, BI2 = {bi, 0.f},
              BH2 = {bh, 0.f}, BO2 = {bo, 0.f};
    // t=0 peel biases (gi = b_ih only)
    const float br0_ = ok ? -(b_ih[fi] + b_hh[fi]) * LOG2E : 0.f;
    const float bz0_ = ok ? -(b_ih[10 + fi] + b_hh[10 + fi]) * LOG2E : 0.f;
    const float bni0 = ok ? b_ih[20 + fi] * S2 : 0.f;

    // ---- initial h (one feature per lane; f>=10 stays exactly 0) ----
    float h = ok ? hidden[(size_t)b * HID + f] : 0.f;

    float* pb = out + (size_t)b * (STEPS * HID) + (size_t)(STEPS - 1) * HID + f;
    float* sHrow = &sH[g * 16];

    // ---- t = 0 peeled: gi = b_ih only (x_0 = 0); raw w_hh dots from LDS ----
    // Produces h1. o_0 = l1(h1) is stored by the first loop iteration.
    {
        float ha[10];
        ha[0] = swz<0>(h); ha[1] = swz<1>(h); ha[2] = swz<2>(h);
        ha[3] = swz<3>(h); ha[4] = swz<4>(h); ha[5] = swz<5>(h);
        ha[6] = swz<6>(h); ha[7] = swz<7>(h); ha[8] = swz<8>(h);
        ha[9] = swz<9>(h);
        float pr = 0.f, pz = 0.f, ph = 0.f;
        #pragma unroll
        for (int k = 0; k < 10; ++k) {
            pr += sWhh[fi * 10 + k] * ha[k];
            pz += sWhh[(10 + fi) * 10 + k] * ha[k];
            ph += sWhh[(20 + fi) * 10 + k] * ha[k];
        }
        float vr = br0_ - pr * LOG2E;
        float vz = bz0_ - pz * LOG2E;
        float r = __builtin_amdgcn_rcpf(1.f + __builtin_amdgcn_exp2f(vr));
        float z = __builtin_amdgcn_rcpf(1.f + __builtin_amdgcn_exp2f(vz));
        float y = bni0 + r * (ph * S2 + bh);
        float n = 1.f - 2.f * __builtin_amdgcn_rcpf(1.f + __builtin_amdgcn_exp2f(y));
        h = ok ? (n + z * (h - n)) : 0.f;
    }

    // ---- anti-phase stagger keyed on the PHYSICAL wave slot (cannot alias) ----
    // HW_REG_HW_ID (id=4), offset 0, size 4 -> WAVE_ID[3:0].
    // imm encoding: ((size-1)<<11) | (offset<<6) | id = (3<<11)|4 = 0x1804.
    {
        int slot = __builtin_amdgcn_s_getreg(0x1804) & 0xF;
        for (int i = 0; i < slot; ++i) __builtin_amdgcn_s_sleep(4);  // ~256cy/unit
    }

    // ---- t = 1 .. 511 : LDS write+broadcast-read gather, 5-deep pk chains ----
    #pragma unroll 1
    for (int t = 1; t < STEPS; ++t) {
        // stage h: all 64 lanes write (rows padded to 16; f>=10 slots unread)
        sHrow[f] = h;
        __builtin_amdgcn_wave_barrier();      // keep write->reads ordered
        __builtin_amdgcn_sched_barrier(0);
        v4f q0 = *(const v4f*)(sHrow);        // h[0..3]  (broadcast read)
        v4f q1 = *(const v4f*)(sHrow + 4);    // h[4..7]
        v2f q2 = *(const v2f*)(sHrow + 8);    // h[8..9]

        v2f h2_0 = __builtin_shufflevector(q0, q0, 0, 1);
        v2f h2_1 = __builtin_shufflevector(q0, q0, 2, 3);
        v2f h2_2 = __builtin_shufflevector(q1, q1, 0, 1);
        v2f h2_3 = __builtin_shufflevector(q1, q1, 2, 3);
        v2f h2_4 = q2;

        // fma-init into bias consts (no accumulator movs)
        v2f ar = wr2[0] * h2_0 + BR2;
        v2f az = wz2[0] * h2_0 + BZ2;
        v2f ai = wi2[0] * h2_0 + BI2;
        v2f ah = wh2[0] * h2_0 + BH2;
        v2f ao = wo2[0] * h2_0 + BO2;
        ar += wr2[1] * h2_1; az += wz2[1] * h2_1; ai += wi2[1] * h2_1;
        ah += wh2[1] * h2_1; ao += wo2[1] * h2_1;
        ar += wr2[2] * h2_2; az += wz2[2] * h2_2; ai += wi2[2] * h2_2;
        ah += wh2[2] * h2_2; ao += wo2[2] * h2_2;
        ar += wr2[3] * h2_3; az += wz2[3] * h2_3; ai += wi2[3] * h2_3;
        ah += wh2[3] * h2_3; ao += wo2[3] * h2_3;
        ar += wr2[4] * h2_4; az += wz2[4] * h2_4; ai += wi2[4] * h2_4;
        ah += wh2[4] * h2_4; ao += wo2[4] * h2_4;

        float arx = ar.x + ar.y;
        float azx = az.x + az.y;
        float aix = ai.x + ai.y;
        float ahx = ah.x + ah.y;
        float o   = ao.x + ao.y;          // = l1(h_t) = o_{t-1}

        // r-gate, then fused z/n update with a single rcp:
        //   h' = (ez*(en-1) + h*(en+1)) / ((en+1)*(1+ez))
        float er = __builtin_amdgcn_exp2f(arx);
        float r  = __builtin_amdgcn_rcpf(1.f + er);
        float ez = __builtin_amdgcn_exp2f(azx);
        float y  = __builtin_fmaf(r, ahx, aix);
        float en = __builtin_amdgcn_exp2f(y);
        float p  = en * ez;
        float tt = h - ez;
        float u  = p + tt;
        float num = __builtin_fmaf(h, en, u);          // ez*en - ez + h*en + h
        float v   = en + ez;
        float den = (p + v) + 1.f;                     // (en+1)*(1+ez)
        h = num * __builtin_amdgcn_rcpf(den);          // padded lanes: h stays 0

        if (ok) pb[0] = o;                 // store o_{t-1} (position STEPS-t)
        pb -= HID;
    }

    // ---- epilogue: o_511 = l1(h_512) at position 0 ----
    {
        v2f h2[5];
        h2[0] = v2f{swz<0>(h), swz<1>(h)};
        h2[1] = v2f{swz<2>(h), swz<3>(h)};
        h2[2] = v2f{swz<4>(h), swz<5>(h)};
        h2[3] = v2f{swz<6>(h), swz<7>(h)};
        h2[4] = v2f{swz<8>(h), swz<9>(h)};
        v2f ao = {bo, 0.f};
        #pragma unroll
        for (int k2 = 0; k2 < 5; ++k2) ao += wo2[k2] * h2[k2];
        if (ok) pb[0] = ao.x + ao.y;
    }
}

extern "C" void kernel_launch(void* const* d_in, const int* in_sizes, int n_in,
                              void* d_out, int out_size, void* d_ws, size_t ws_size,
                              hipStream_t stream) {
    (void)in_sizes; (void)n_in; (void)d_ws; (void)ws_size; (void)out_size;
    dim3 grid(2048), block(64);   // 4 batches/wave, 2048 waves -> 2 waves per SIMD
    gru_decoder_kernel<<<grid, block, 0, stream>>>(
        (const float*)d_in[0], (const float*)d_in[1], (const float*)d_in[2],
        (const float*)d_in[3], (const float*)d_in[4], (const float*)d_in[5],
        (const float*)d_in[6], (const float*)d_in[7], (const float*)d_in[8],
        (float*)d_out);
}